// Round 1
// baseline (237.261 us; speedup 1.0000x reference)
//
#include <hip/hip_runtime.h>
#include <hip/hip_bf16.h>

#define B_ 128
#define S_ 48
#define W_ 12
#define V_ 32000
#define SYM_ 128
#define H_ 256
#define E_ 48
#define R_ 24
#define TM 16

// ---------------------------------------------------------------------------
// Kernel 1: ssum[b,s,c] = sum_w we[story[b,s,w],c]*pe[w,c];  qsum likewise.
// ---------------------------------------------------------------------------
__global__ __launch_bounds__(128) void ssum_kernel(
    const int* __restrict__ story, const int* __restrict__ query,
    const float* __restrict__ we, const float* __restrict__ pe,
    float* __restrict__ ssum, float* __restrict__ qsum)
{
    int i = blockIdx.x;
    int c = threadIdx.x;
    const int* idxp;
    float* outp;
    if (i < B_ * S_) {
        idxp = story + (size_t)i * W_;
        outp = ssum + (size_t)i * SYM_;
    } else {
        int b = i - B_ * S_;
        idxp = query + (size_t)b * W_;
        outp = qsum + (size_t)b * SYM_;
    }
    float acc = 0.f;
#pragma unroll
    for (int w = 0; w < W_; ++w) {
        int id = idxp[w];  // uniform across lanes -> scalar load
        acc = fmaf(we[(size_t)id * SYM_ + c], pe[w * SYM_ + c], acc);
    }
    outp[c] = acc;
}

// ---------------------------------------------------------------------------
// Kernel 2: generic 2-layer tanh MLP, 128->256->OUT, TM rows per block.
// grid.y = nE + nR heads; m < nE uses entity weights (OUT=48), else role (24).
// ---------------------------------------------------------------------------
__global__ __launch_bounds__(256) void mlp_kernel(
    const float* __restrict__ x, int M,
    const float* __restrict__ W1e, const float* __restrict__ b1e,
    const float* __restrict__ W2e, const float* __restrict__ b2e,
    int nE,
    const float* __restrict__ W1r, const float* __restrict__ b1r,
    const float* __restrict__ W2r, const float* __restrict__ b2r,
    float* __restrict__ outE,   // [nE][M][48]
    float* __restrict__ outR)   // [nR][M][24]
{
    int m = blockIdx.y;
    int row0 = blockIdx.x * TM;
    const float *W1, *b1, *W2, *b2;
    float* out;
    int OUT;
    if (m < nE) {
        W1 = W1e + (size_t)m * SYM_ * H_;
        b1 = b1e + (size_t)m * H_;
        W2 = W2e + (size_t)m * H_ * E_;
        b2 = b2e + (size_t)m * E_;
        out = outE + (size_t)m * M * E_;
        OUT = E_;
    } else {
        int mr = m - nE;
        W1 = W1r + (size_t)mr * SYM_ * H_;
        b1 = b1r + (size_t)mr * H_;
        W2 = W2r + (size_t)mr * H_ * R_;
        b2 = b2r + (size_t)mr * R_;
        out = outR + (size_t)mr * M * R_;
        OUT = R_;
    }

    int t = threadIdx.x;
    __shared__ __align__(16) float xs[TM][SYM_];
    __shared__ __align__(16) float hs[TM][H_];

    for (int i = t; i < TM * SYM_; i += 256)
        xs[i / SYM_][i % SYM_] = x[(size_t)row0 * SYM_ + i];
    __syncthreads();

    // layer 1: h[row][t] = tanh(sum_k x[row][k]*W1[k][t] + b1[t])
    float acc[TM];
#pragma unroll
    for (int row = 0; row < TM; ++row) acc[row] = 0.f;

    const float4* xs4 = reinterpret_cast<const float4*>(&xs[0][0]);  // row stride 32 float4
    for (int k4 = 0; k4 < SYM_ / 4; ++k4) {
        float w0 = W1[(size_t)(4 * k4 + 0) * H_ + t];
        float w1 = W1[(size_t)(4 * k4 + 1) * H_ + t];
        float w2 = W1[(size_t)(4 * k4 + 2) * H_ + t];
        float w3 = W1[(size_t)(4 * k4 + 3) * H_ + t];
#pragma unroll
        for (int row = 0; row < TM; ++row) {
            float4 xv = xs4[row * (SYM_ / 4) + k4];
            acc[row] = fmaf(xv.x, w0, fmaf(xv.y, w1, fmaf(xv.z, w2, fmaf(xv.w, w3, acc[row]))));
        }
    }
    float bb = b1[t];
#pragma unroll
    for (int row = 0; row < TM; ++row) hs[row][t] = tanhf(acc[row] + bb);
    __syncthreads();

    // layer 2: out[row][o] = tanh(sum_k h[row][k]*W2[k][o] + b2[o])
    for (int idx = t; idx < TM * OUT; idx += 256) {
        int row = idx / OUT;
        int o = idx - row * OUT;
        const float4* hr = reinterpret_cast<const float4*>(&hs[row][0]);
        float a = 0.f;
        for (int k4 = 0; k4 < H_ / 4; ++k4) {
            float4 h = hr[k4];
            a = fmaf(h.x, W2[(size_t)(4 * k4 + 0) * OUT + o],
                fmaf(h.y, W2[(size_t)(4 * k4 + 1) * OUT + o],
                fmaf(h.z, W2[(size_t)(4 * k4 + 2) * OUT + o],
                fmaf(h.w, W2[(size_t)(4 * k4 + 3) * OUT + o], a))));
        }
        out[(size_t)(row0 + row) * OUT + o] = tanhf(a + b2[o]);
    }
}

// ---------------------------------------------------------------------------
// Kernel 3: the sequential TPR scan. grid (2 f-halves, B batches), 576 thr.
// Thread owns TPR[e=0..47, r, f] column in registers (r = t%24, f = f0+t/24).
// TPR output layout: [B][E][F=48][R=24]  (fully coalesced store).
// ---------------------------------------------------------------------------
__global__ __launch_bounds__(576) void scan_kernel(
    const float* __restrict__ eg,   // [2][B][S][48]
    const float* __restrict__ rg,   // [3][B][S][24]
    float* __restrict__ TPR)        // [B][48][48][24]
{
    const int b = blockIdx.y;
    const int f0 = blockIdx.x * 24;
    const int t = threadIdx.x;
    const int r = t % 24;
    const int fl = t / 24;
    const int f = f0 + fl;

    float T[E_];
#pragma unroll
    for (int e = 0; e < E_; ++e) T[e] = 0.f;

    __shared__ float part[3][24][25];
    __shared__ float hat[3][24];

    const size_t bs48 = (size_t)b * S_ * 48;
    const size_t bs24 = (size_t)b * S_ * 24;
    const float* e1g = eg + bs48;
    const float* e2g = eg + (size_t)B_ * S_ * 48 + bs48;
    const float* r1g = rg + bs24;
    const float* r2g = rg + (size_t)B_ * S_ * 24 + bs24;
    const float* r3g = rg + (size_t)2 * B_ * S_ * 24 + bs24;

    for (int s = 0; s < S_; ++s) {
        const float* e1p = e1g + s * 48;
        const float* e2p = e2g + s * 48;
        float r1v = r1g[s * 24 + r];
        float r2v = r2g[s * 24 + r];
        float r3v = r3g[s * 24 + r];

        float s1 = 0.f, s2 = 0.f;
#pragma unroll
        for (int e = 0; e < E_; ++e) {
            float a = e1p[e];   // uniform -> scalar load
            float c = e2p[e];
            s1 = fmaf(a, T[e], s1);
            s2 = fmaf(c, T[e], s2);
        }
        part[0][fl][r] = r1v * s1;
        part[1][fl][r] = r2v * s1;
        part[2][fl][r] = r3v * s2;
        __syncthreads();
        if (t < 72) {
            int h = t / 24, ff = t - (t / 24) * 24;
            float a0 = 0.f;
#pragma unroll
            for (int j = 0; j < 24; ++j) a0 += part[h][ff][j];
            hat[h][ff] = a0;
        }
        __syncthreads();
        float w = hat[0][fl];
        float mm = hat[1][fl];
        float bh = hat[2][fl];
        float e1f = e1p[f];
        float e2f = e2p[f];
        float wm = fmaf(r1v, e2f - w, r2v * (w - mm));  // write+move at (r,f)
        float bl = r3v * (e1f - bh);                    // backlink at (r,f)
#pragma unroll
        for (int e = 0; e < E_; ++e) {
            float a = e1p[e];
            float c = e2p[e];
            T[e] = fmaf(a, wm, fmaf(c, bl, T[e]));
        }
        // 2 barriers/step suffice: hat writes (next iter) gated by barrier 1,
        // part writes (next iter) gated by this iter's barrier 2.
    }

#pragma unroll
    for (int e = 0; e < E_; ++e)
        TPR[(((size_t)b * E_ + e) * 48 + f) * 24 + r] = T[e];
}

// ---------------------------------------------------------------------------
// Kernel 4: inference contractions + LayerNorms. One block per batch.
// x_c[f] = sum_{e,r} a[e]*qr_c[r]*T[e,r,f]; a chains qe1 -> i1 -> i2.
// ---------------------------------------------------------------------------
__global__ __launch_bounds__(576) void infer_kernel(
    const float* __restrict__ TPR,   // [B][48][48][24]
    const float* __restrict__ qe1,   // [B][48]
    const float* __restrict__ qr,    // [3][B][24]
    const float* __restrict__ ln_gain, const float* __restrict__ ln_bias,  // [3][48]
    float* __restrict__ isum)        // [B][48]
{
    int b = blockIdx.x;
    int t = threadIdx.x;
    int f = t / 12;    // 0..47
    int rr = t % 12;   // handles r = rr and rr+12

    __shared__ float part[48][13];
    __shared__ float xv[48];
    __shared__ float av[48];
    __shared__ float acc3[48];

    const float* Tb = TPR + (size_t)b * E_ * 48 * 24;
    if (t < 48) {
        av[t] = qe1[b * 48 + t];
        acc3[t] = 0.f;
    }
    __syncthreads();

    for (int c = 0; c < 3; ++c) {
        const float* qrc = qr + ((size_t)c * B_ + b) * 24;
        float q0 = qrc[rr];
        float q1 = qrc[rr + 12];
        float p = 0.f;
#pragma unroll 8
        for (int e = 0; e < E_; ++e) {
            float a = av[e];
            const float* row = Tb + ((size_t)e * 48 + f) * 24;
            p = fmaf(a, fmaf(q0, row[rr], q1 * row[rr + 12]), p);
        }
        part[f][rr] = p;
        __syncthreads();
        if (t < 48) {
            float x = 0.f;
#pragma unroll
            for (int j = 0; j < 12; ++j) x += part[t][j];
            xv[t] = x;
        }
        __syncthreads();
        if (t < 48) {
            float mu = 0.f;
#pragma unroll
            for (int j = 0; j < 48; ++j) mu += xv[j];
            mu *= (1.f / 48.f);
            float var = 0.f;
#pragma unroll
            for (int j = 0; j < 48; ++j) {
                float d = xv[j] - mu;
                var = fmaf(d, d, var);
            }
            var *= (1.f / 48.f);
            float inv = 1.f / sqrtf(var + 1e-6f);
            float o = ln_gain[c * 48 + t] * (xv[t] - mu) * inv + ln_bias[c * 48 + t];
            av[t] = o;
            acc3[t] += o;
        }
        __syncthreads();
    }
    if (t < 48) isum[b * 48 + t] = acc3[t];
}

// ---------------------------------------------------------------------------
// Kernel 5: logits[b,v] = sum_e isum[b,e] * Z[e,v]
// ---------------------------------------------------------------------------
__global__ __launch_bounds__(256) void logits_kernel(
    const float* __restrict__ isum,  // [B][48]
    const float* __restrict__ Z,     // [48][V]
    float* __restrict__ out)         // [B][V]
{
    int v = blockIdx.x * 256 + threadIdx.x;
    int b0 = blockIdx.y * (B_ / 2);
    float z[E_];
#pragma unroll
    for (int e = 0; e < E_; ++e) z[e] = Z[(size_t)e * V_ + v];
    for (int b = b0; b < b0 + B_ / 2; ++b) {
        float a = 0.f;
#pragma unroll
        for (int e = 0; e < E_; ++e) a = fmaf(isum[b * 48 + e], z[e], a);  // uniform -> s_load
        out[(size_t)b * V_ + v] = a;
    }
}

// ---------------------------------------------------------------------------
extern "C" void kernel_launch(void* const* d_in, const int* in_sizes, int n_in,
                              void* d_out, int out_size, void* d_ws, size_t ws_size,
                              hipStream_t stream) {
    const int* story  = (const int*)d_in[0];
    const int* query  = (const int*)d_in[1];
    const float* we   = (const float*)d_in[2];
    const float* pe   = (const float*)d_in[3];
    const float* Z    = (const float*)d_in[4];
    const float* ue_W1 = (const float*)d_in[5];
    const float* ue_b1 = (const float*)d_in[6];
    const float* ue_W2 = (const float*)d_in[7];
    const float* ue_b2 = (const float*)d_in[8];
    const float* ur_W1 = (const float*)d_in[9];
    const float* ur_b1 = (const float*)d_in[10];
    const float* ur_W2 = (const float*)d_in[11];
    const float* ur_b2 = (const float*)d_in[12];
    const float* ie_W1 = (const float*)d_in[13];
    const float* ie_b1 = (const float*)d_in[14];
    const float* ie_W2 = (const float*)d_in[15];
    const float* ie_b2 = (const float*)d_in[16];
    const float* ir_W1 = (const float*)d_in[17];
    const float* ir_b1 = (const float*)d_in[18];
    const float* ir_W2 = (const float*)d_in[19];
    const float* ir_b2 = (const float*)d_in[20];
    const float* ln_g  = (const float*)d_in[21];
    const float* ln_b  = (const float*)d_in[22];
    float* out = (float*)d_out;

    float* ws = (float*)d_ws;
    float* ssum = ws;                                  // 6144*128   = 786432
    float* qsum = ssum + (size_t)B_ * S_ * SYM_;       // 128*128    = 16384
    float* eout = qsum + (size_t)B_ * SYM_;            // 2*6144*48  = 589824
    float* rout = eout + (size_t)2 * B_ * S_ * E_;     // 3*6144*24  = 442368
    float* qe1  = rout + (size_t)3 * B_ * S_ * R_;     // 128*48     = 6144
    float* qrr  = qe1 + (size_t)B_ * E_;               // 3*128*24   = 9216
    float* TPR  = qrr + (size_t)3 * B_ * R_;           // 128*48*48*24 = 3538944
    float* isum = TPR + (size_t)B_ * E_ * 48 * 24;     // 128*48     = 6144

    ssum_kernel<<<B_ * S_ + B_, 128, 0, stream>>>(story, query, we, pe, ssum, qsum);

    mlp_kernel<<<dim3((B_ * S_) / TM, 5), 256, 0, stream>>>(
        ssum, B_ * S_, ue_W1, ue_b1, ue_W2, ue_b2, 2,
        ur_W1, ur_b1, ur_W2, ur_b2, eout, rout);

    mlp_kernel<<<dim3(B_ / TM, 4), 256, 0, stream>>>(
        qsum, B_, ie_W1, ie_b1, ie_W2, ie_b2, 1,
        ir_W1, ir_b1, ir_W2, ir_b2, qe1, qrr);

    scan_kernel<<<dim3(2, B_), 576, 0, stream>>>(eout, rout, TPR);

    infer_kernel<<<B_, 576, 0, stream>>>(TPR, qe1, qrr, ln_g, ln_b, isum);

    logits_kernel<<<dim3(V_ / 256, 2), 256, 0, stream>>>(isum, Z, out);
}